// Round 9
// baseline (198.622 us; speedup 1.0000x reference)
//
#include <hip/hip_runtime.h>
#include <hip/hip_bf16.h>

typedef __bf16 bf16_t;
typedef __bf16 bf16x8 __attribute__((ext_vector_type(8)));
typedef __bf16 bf16x4 __attribute__((ext_vector_type(4)));
typedef __bf16 bf16x2 __attribute__((ext_vector_type(2)));
typedef float  f32x4  __attribute__((ext_vector_type(4)));

#define LN_EPS 1e-5f

// B=8, T=512, C=768 -> M = 4096, 4C = 3072

// ---------------- fp32 -> bf16 conversion ----------------
__global__ __launch_bounds__(256) void k_cvt4(const float* __restrict__ s0,
                                              const float* __restrict__ s1,
                                              const float* __restrict__ s2,
                                              const float* __restrict__ s3,
                                              bf16_t* __restrict__ dst, int n4) {
    const float* s = (blockIdx.y == 0) ? s0 : (blockIdx.y == 1) ? s1 : (blockIdx.y == 2) ? s2 : s3;
    bf16_t* d = dst + (size_t)blockIdx.y * ((size_t)n4 * 4);
    int i = blockIdx.x * 256 + threadIdx.x;
    if (i < n4) {
        float4 v = ((const float4*)s)[i];
        bf16x4 o;
        o.x = (bf16_t)v.x; o.y = (bf16_t)v.y; o.z = (bf16_t)v.z; o.w = (bf16_t)v.w;
        ((bf16x4*)d)[i] = o;
    }
}

__global__ __launch_bounds__(256) void k_cvt2(const float* __restrict__ s0,
                                              const float* __restrict__ s1,
                                              bf16_t* __restrict__ dst, int n4) {
    const float* s = (blockIdx.y == 0) ? s0 : s1;
    bf16_t* d = dst + (size_t)blockIdx.y * ((size_t)n4 * 4);
    int i = blockIdx.x * 256 + threadIdx.x;
    if (i < n4) {
        float4 v = ((const float4*)s)[i];
        bf16x4 o;
        o.x = (bf16_t)v.x; o.y = (bf16_t)v.y; o.z = (bf16_t)v.z; o.w = (bf16_t)v.w;
        ((bf16x4*)d)[i] = o;
    }
}

// ---------------- LayerNorm (one block per row of C=768), bf16 out ----------------
__global__ __launch_bounds__(256) void k_ln(const float* __restrict__ x,
                                            const float* __restrict__ w,
                                            const float* __restrict__ b,
                                            bf16_t* __restrict__ out, int C) {
    int row = blockIdx.x;
    const float* xr = x + (long)row * C;
    int tid = threadIdx.x;
    float s = 0.f, s2 = 0.f;
    for (int i = tid; i < C; i += 256) { float v = xr[i]; s += v; s2 += v * v; }
    for (int m = 32; m; m >>= 1) { s += __shfl_xor(s, m, 64); s2 += __shfl_xor(s2, m, 64); }
    __shared__ float red[8];
    int wv = tid >> 6;
    if ((tid & 63) == 0) { red[wv] = s; red[4 + wv] = s2; }
    __syncthreads();
    float ts  = red[0] + red[1] + red[2] + red[3];
    float ts2 = red[4] + red[5] + red[6] + red[7];
    float mu  = ts / C;
    float var = ts2 / C - mu * mu;
    float rstd = rsqrtf(var + LN_EPS);
    bf16_t* orow = out + (long)row * C;
    for (int i = tid; i < C; i += 256)
        orow[i] = (bf16_t)((xr[i] - mu) * rstd * w[i] + b[i]);
}

// ---------------- bf16 MFMA GEMM: reg-staged (T14), 128x128 tile, 4 waves ---------
// C[M][N](+=) A[M][Kslice] * Bw[N][Kslice]^T.  NO global_load_lds: loads go
// global->VGPR (issued one K-step early, high-throughput, per-wave counted waits)
// then VGPR->ds_write just before a lgkm-only barrier. vmcnt is NEVER drained at a
// barrier, so loads stay in flight across it (the R2-R8 wall was the glds16 DMA
// pipe being drained per K-step).
// Geometry: 4 waves (2x2), per-wave 64x64 out (acc 4x4), BK=32, 24 K-iters.
// LDS: 2 x (128x32 A + 128x32 B) = 32 KB -> 3 blocks/CU at grid 768.
// LDS slots XOR'd: phys = log ^ (r&3) ^ ((r>>2)&3)  (bank-balanced read+write).
// XCD slab: 8bm x 12cix per XCD -> ~3.9 MB L2 set.
// EPI 0: store bf16   EPI 1: store bf16(relu^2)   EPI 3: atomicAdd fp32
template <int EPI>
__global__ __launch_bounds__(256, 3) void k_gemm_rs(const bf16_t* __restrict__ A,
                                                    const bf16_t* __restrict__ Bw,
                                                    void* __restrict__ Cout,
                                                    int N, int Ktot, int nbn, int nks) {
    __shared__ __align__(16) bf16_t As[2][128][32];  // 16 KB
    __shared__ __align__(16) bf16_t Bs[2][128][32];  // 16 KB
    const int tid  = threadIdx.x;
    const int lane = tid & 63, wid = tid >> 6;
    const int wm = (wid >> 1) * 64, wn = (wid & 1) * 64;

    // XCD slab swizzle: grid == 768; per XCD 96 blocks = 8 bm x 12 cix
    int bid = blockIdx.x;
    int xcd = bid & 7, loc = bid >> 3;               // loc 0..95
    int bm  = (xcd >> 1) * 8 + loc / 12;             // 0..31
    int cix = (xcd & 1) * 12 + loc % 12;             // 0..23
    int ks  = cix / nbn;
    int bn  = cix % nbn;

    const int fr  = lane & 15;
    // read phys 16B-slot: ko ^ (fr&3) ^ (fr>>2)  (bank-balanced, <=2-way)
    const int swk = (((lane >> 4) ^ (fr & 3) ^ (fr >> 2)) & 3) * 8;  // elems

    f32x4 acc[4][4];
#pragma unroll
    for (int i = 0; i < 4; i++)
#pragma unroll
        for (int j = 0; j < 4; j++) acc[i][j] = (f32x4){0.f, 0.f, 0.f, 0.f};

    // staging map: thread t -> row (t&127), logical 16B-slots sl0=(t>>7)*2, sl0+1
    const int srow = tid & 127;
    const int sl0  = (tid >> 7) * 2;
    const int f_r  = (srow & 3) ^ ((srow >> 2) & 3);
    const int wph0 = ((sl0 ^ f_r) & 3) * 8;          // phys col (elems), q=0
    const int wph1 = (((sl0 + 1) ^ f_r) & 3) * 8;    // q=1
    const size_t ksoff = (size_t)ks * 768;
    const bf16_t* gA = A  + (size_t)(bm * 128 + srow) * Ktot + ksoff + sl0 * 8;
    const bf16_t* gB = Bw + (size_t)(bn * 128 + srow) * Ktot + ksoff + sl0 * 8;

    uint4 rA0, rA1, rB0, rB1;   // in-flight staging registers (one K-step ahead)

#define LOADREG(kt)                                                  \
    do {                                                             \
        const bf16_t* a = gA + (size_t)(kt) * 32;                    \
        const bf16_t* b = gB + (size_t)(kt) * 32;                    \
        rA0 = *(const uint4*)(a);                                    \
        rA1 = *(const uint4*)(a + 8);                                \
        rB0 = *(const uint4*)(b);                                    \
        rB1 = *(const uint4*)(b + 8);                                \
    } while (0)

#define WRITE(buf)                                                   \
    do {                                                             \
        *(uint4*)&As[buf][srow][wph0] = rA0;                         \
        *(uint4*)&As[buf][srow][wph1] = rA1;                         \
        *(uint4*)&Bs[buf][srow][wph0] = rB0;                         \
        *(uint4*)&Bs[buf][srow][wph1] = rB1;                         \
    } while (0)

#define COMPUTE(buf)                                                                         \
    do {                                                                                     \
        bf16x8 af[4], bfr[4];                                                                \
        _Pragma("unroll")                                                                    \
        for (int mi = 0; mi < 4; mi++) af[mi] = *(const bf16x8*)&As[buf][wm + mi * 16 + fr][swk]; \
        _Pragma("unroll")                                                                    \
        for (int ni = 0; ni < 4; ni++) bfr[ni] = *(const bf16x8*)&Bs[buf][wn + ni * 16 + fr][swk]; \
        __builtin_amdgcn_s_setprio(1);                                                       \
        _Pragma("unroll")                                                                    \
        for (int mi = 0; mi < 4; mi++)                                                       \
            _Pragma("unroll")                                                                \
            for (int ni = 0; ni < 4; ni++)                                                   \
                acc[mi][ni] = __builtin_amdgcn_mfma_f32_16x16x32_bf16(af[mi], bfr[ni], acc[mi][ni], 0, 0, 0); \
        __builtin_amdgcn_s_setprio(0);                                                       \
    } while (0)

// lgkm-only barrier: ds ops drained, vmem loads STAY IN FLIGHT across it
#define BAR()                                                        \
    do {                                                             \
        asm volatile("s_waitcnt lgkmcnt(0)" ::: "memory");           \
        __builtin_amdgcn_s_barrier();                                \
        __builtin_amdgcn_sched_barrier(0);                           \
    } while (0)

    // prologue: LDS[0] = tile 0; regs <- tile 1 (in flight)
    LOADREG(0);
    WRITE(0);            // compiler inserts the vmcnt wait for tile0 loads here
    LOADREG(1);
    BAR();

    int cur = 0;
    for (int t = 0; t < 24; ++t) {
        if (t < 23) WRITE(cur ^ 1);     // waits (counted) only on tile t+1 regs
        if (t < 22) LOADREG(t + 2);     // issue next loads; fly during COMPUTE
        COMPUTE(cur);
        BAR();                          // ds drained; vmem still outstanding
        cur ^= 1;
    }

#undef LOADREG
#undef WRITE
#undef COMPUTE
#undef BAR

    const int row0 = bm * 128 + wm, col0 = bn * 128 + wn;
#pragma unroll
    for (int mi = 0; mi < 4; mi++) {
#pragma unroll
        for (int ni = 0; ni < 4; ni++) {
            int row = row0 + mi * 16 + (lane >> 4) * 4;   // C/D: col=lane&15, row=(lane>>4)*4+r
            int col = col0 + ni * 16 + (lane & 15);
#pragma unroll
            for (int r = 0; r < 4; r++) {
                float val = acc[mi][ni][r];
                size_t off = (size_t)(row + r) * N + col;
                if (EPI == 0) {
                    ((bf16_t*)Cout)[off] = (bf16_t)val;
                } else if (EPI == 1) {
                    float t = fmaxf(val, 0.f);
                    ((bf16_t*)Cout)[off] = (bf16_t)(t * t);
                } else {
                    atomicAdd(&((float*)Cout)[off], val);
                }
            }
        }
    }
}

// ---------------- WKV chunked scan (y4 bf16), 2 channels/thread ----------------
// y4 layout per (b,t): [ r(768) | k(768) | v(768) | router(768) ]
__global__ __launch_bounds__(256) void k_scan_local(const bf16_t* __restrict__ y4,
                                                    const float* __restrict__ tmw,
                                                    float* __restrict__ wkvl,
                                                    float* __restrict__ states) {
    int idx = blockIdx.x * 256 + threadIdx.x;  // 8*16*384 = 49152
    int cp  = idx % 384;
    int rem = idx / 384;
    int ch  = rem & 15;
    int b   = rem >> 4;
    int c   = cp * 2;
    float d0 = expf(-expf(tmw[c]));
    float d1 = expf(-expf(tmw[c + 1]));
    const bf16_t* base = y4 + ((size_t)(b * 512 + ch * 32)) * 3072 + c;
    float*        wout = wkvl + ((size_t)(b * 512 + ch * 32)) * 768 + c;
    float s0 = 0.f, s1 = 0.f;
#pragma unroll 4
    for (int i = 0; i < 32; i++) {
        bf16x2 k2 = *(const bf16x2*)(base + (size_t)i * 3072 + 768);
        bf16x2 v2 = *(const bf16x2*)(base + (size_t)i * 3072 + 1536);
        s0 = s0 * d0 + (float)k2.x * (float)v2.x;
        s1 = s1 * d1 + (float)k2.y * (float)v2.y;
        *(float2*)(wout + (size_t)i * 768) = make_float2(s0, s1);
    }
    *(float2*)(states + ((size_t)(b * 16 + ch)) * 768 + c) = make_float2(s0, s1);
}

__global__ __launch_bounds__(256) void k_scan_carry(const float* __restrict__ states,
                                                    const float* __restrict__ tmw,
                                                    float* __restrict__ carries) {
    int idx = blockIdx.x * 256 + threadIdx.x;  // b*768 + c
    int c = idx % 768, b = idx / 768;
    float dL = expf(-expf(tmw[c]) * 32.f);
    float s = 0.f;
    for (int ch = 0; ch < 16; ch++) {
        size_t o = ((size_t)(b * 16 + ch)) * 768 + c;
        carries[o] = s;
        s = s * dL + states[o];
    }
}

// ---------------- mix + LN2 fused: one block per (b,t) row ----------------
// out = x + r*((wkv_local + carry*d^(tmod+1)) * sigmoid(router));  xx2 = LN2(out) bf16
// (out is d_out; the final GEMM atomically adds the channel-mix on top)
__global__ __launch_bounds__(256) void k_mix_ln(const bf16_t* __restrict__ y4,
                                                const float* __restrict__ wkvl,
                                                const float* __restrict__ carries,
                                                const float* __restrict__ tmw,
                                                const float* __restrict__ x,
                                                const float* __restrict__ w2,
                                                const float* __restrict__ b2,
                                                float* __restrict__ out,
                                                bf16_t* __restrict__ xx2) {
    int bt = blockIdx.x;
    int t = bt & 511, b = bt >> 9;
    int tid = threadIdx.x;
    const bf16_t* yrow = y4 + (size_t)bt * 3072;
    const float*  wl   = wkvl + (size_t)bt * 768;
    const float*  cr   = carries + ((size_t)(b * 16) + (t >> 5)) * 768;
    const float*  xr   = x + (size_t)bt * 768;
    float tn = (float)((t & 31) + 1);

    float vals[3];
    float s = 0.f, s2 = 0.f;
#pragma unroll
    for (int j = 0; j < 3; j++) {
        int c = tid + j * 256;
        float rr = (float)yrow[c];
        float gg = (float)yrow[c + 2304];
        float wk = wl[c] + cr[c] * expf(-expf(tmw[c]) * tn);
        float sig = 1.f / (1.f + expf(-gg));
        float o = fmaf(rr, wk * sig, xr[c]);
        vals[j] = o; s += o; s2 += o * o;
    }
    for (int m = 32; m; m >>= 1) { s += __shfl_xor(s, m, 64); s2 += __shfl_xor(s2, m, 64); }
    __shared__ float red[8];
    int wv = tid >> 6;
    if ((tid & 63) == 0) { red[wv] = s; red[4 + wv] = s2; }
    __syncthreads();
    float ts  = red[0] + red[1] + red[2] + red[3];
    float ts2 = red[4] + red[5] + red[6] + red[7];
    float mu  = ts * (1.f / 768.f);
    float var = ts2 * (1.f / 768.f) - mu * mu;
    float rstd = rsqrtf(var + LN_EPS);
    float* orow = out + (size_t)bt * 768;
    bf16_t* xo = xx2 + (size_t)bt * 768;
#pragma unroll
    for (int j = 0; j < 3; j++) {
        int c = tid + j * 256;
        orow[c] = vals[j];
        xo[c] = (bf16_t)((vals[j] - mu) * rstd * w2[c] + b2[c]);
    }
}

// ---------------- host-side launch ----------------
extern "C" void kernel_launch(void* const* d_in, const int* in_sizes, int n_in,
                              void* d_out, int out_size, void* d_ws, size_t ws_size,
                              hipStream_t stream) {
    const float* x    = (const float*)d_in[0];
    const float* ln1w = (const float*)d_in[1];
    const float* ln1b = (const float*)d_in[2];
    const float* Wr   = (const float*)d_in[3];
    const float* Wk   = (const float*)d_in[4];
    const float* Wv   = (const float*)d_in[5];
    const float* tmw  = (const float*)d_in[6];
    const float* Wrt  = (const float*)d_in[7];
    const float* ln2w = (const float*)d_in[8];
    const float* ln2b = (const float*)d_in[9];
    const float* Wck  = (const float*)d_in[10];
    const float* Wcv  = (const float*)d_in[11];
    float* out = (float*)d_out;
    char* ws = (char*)d_ws;

    // workspace layout (bytes)
    bf16_t* xx     = (bf16_t*)(ws + 0);          // 4096*768 bf16 (xx, reused as xx2)
    bf16_t* wcat   = (bf16_t*)(ws + 6291456);    // [4][768][768] bf16 (r,k,v,router)
    bf16_t* wckb   = (bf16_t*)(ws + 11010048);   // [3072][768] bf16
    bf16_t* wcvb   = (bf16_t*)(ws + 15728640);   // [768][3072] bf16
    bf16_t* y4     = (bf16_t*)(ws + 20447232);   // [4096][3072] bf16
    bf16_t* kcm    = (bf16_t*)(ws + 20447232);   // reuses y4 after mix
    float*  wkvl   = (float*)(ws + 70778880);    // [4096][768] fp32
    float*  states = (float*)(ws + 83361792);    // [8][16][768]
    float*  carr   = (float*)(ws + 83755008);    // [8][16][768]

    // 1) weights -> bf16
    const int n768 = 768 * 768 / 4;
    const int nbig = 3072 * 768 / 4;
    k_cvt4<<<dim3(576, 4), dim3(256), 0, stream>>>(Wr, Wk, Wv, Wrt, wcat, n768);
    k_cvt2<<<dim3(2304, 2), dim3(256), 0, stream>>>(Wck, Wcv, wckb, nbig);

    // 2) LN1
    k_ln<<<dim3(4096), dim3(256), 0, stream>>>(x, ln1w, ln1b, xx, 768);

    // 3) fused r|k|v|router GEMM: y4 = xx @ wcat^T  (M=4096, N=3072, Ktot=768)
    k_gemm_rs<0><<<dim3(768), dim3(256), 0, stream>>>(xx, wcat, (void*)y4, 3072, 768, 24, 1);

    // 4) wkv scan + mix(+LN2): writes x1 -> d_out, xx2 -> xx
    k_scan_local<<<dim3(192), dim3(256), 0, stream>>>(y4, tmw, wkvl, states);
    k_scan_carry<<<dim3(24), dim3(256), 0, stream>>>(states, tmw, carr);
    k_mix_ln<<<dim3(4096), dim3(256), 0, stream>>>(y4, wkvl, carr, tmw, x, ln2w, ln2b, out, xx);

    // 5) k_cm = bf16(relu(xx2 @ Wck^T)^2)  (M=4096, N=3072, Ktot=768)
    k_gemm_rs<1><<<dim3(768), dim3(256), 0, stream>>>(xx, wckb, (void*)kcm, 3072, 768, 24, 1);

    // 6) out += k_cm @ Wcv^T  (M=4096, N=768, Ktot=3072), split-K=4, fp32 atomics
    k_gemm_rs<3><<<dim3(768), dim3(256), 0, stream>>>(kcm, wcvb, (void*)out, 768, 3072, 6, 4);
}